// Round 8
// baseline (555.787 us; speedup 1.0000x reference)
//
#include <hip/hip_runtime.h>
#include <math.h>

// Problem constants (match reference)
#define NB   64     // num_groups (B)
#define NG   32     // group_size (G)
#define ND   2000   // output dim D
#define NM   16     // m_samples
#define NE   16     // noise dim
#define NDIN 256
#define NK   272    // DIN + E
#define NCH  4      // loss d-chunks (500 d each)

__device__ __forceinline__ float clampf(float v, float lo, float hi) {
    return fminf(fmaxf(v, lo), hi);
}

__device__ __forceinline__ float softplusf(float v) {
    return (v > 20.f) ? v : log1pf(expf(v));
}

// Fully-packed butterfly: reduce v[0..31] (per-g partials) across 64 lanes in
// 32 shuffles.  Returns the wave total for g = (lane>>1)&31 (dup on pairs).
__device__ __forceinline__ float wave_sum32(float v[NG], int lane) {
    {   const bool hi = (lane & 32) != 0;
        #pragma unroll
        for (int k = 0; k < 16; ++k) {
            float s = hi ? v[k] : v[k + 16];
            float r = __shfl_xor(s, 32);
            v[k] = (hi ? v[k + 16] : v[k]) + r;
        }
    }
    {   const bool hi = (lane & 16) != 0;
        #pragma unroll
        for (int k = 0; k < 8; ++k) {
            float s = hi ? v[k] : v[k + 8];
            float r = __shfl_xor(s, 16);
            v[k] = (hi ? v[k + 8] : v[k]) + r;
        }
    }
    {   const bool hi = (lane & 8) != 0;
        #pragma unroll
        for (int k = 0; k < 4; ++k) {
            float s = hi ? v[k] : v[k + 4];
            float r = __shfl_xor(s, 8);
            v[k] = (hi ? v[k + 4] : v[k]) + r;
        }
    }
    {   const bool hi = (lane & 4) != 0;
        #pragma unroll
        for (int k = 0; k < 2; ++k) {
            float s = hi ? v[k] : v[k + 2];
            float r = __shfl_xor(s, 4);
            v[k] = (hi ? v[k + 2] : v[k]) + r;
        }
    }
    {   const bool hi = (lane & 2) != 0;
        float s = hi ? v[0] : v[1];
        float r = __shfl_xor(s, 2);
        v[0] = (hi ? v[1] : v[0]) + r;
    }
    v[0] += __shfl_xor(v[0], 1);
    return v[0];
}

// ---------------------------------------------------------------------------
// K0: per-b g-sums of x and noise_loss -> sums[b][0..255]=xs, [256..511]=ns.
// ---------------------------------------------------------------------------
extern "C" __global__ __launch_bounds__(256)
void k0_sums(const float* __restrict__ x, const float* __restrict__ nl,
             float* __restrict__ sums) {
    const int b = blockIdx.x, t = threadIdx.x;
    const float* xb = x + (size_t)b * NG * NDIN;
    float s = 0.f;
    for (int g = 0; g < NG; ++g) s += xb[g * NDIN + t];
    sums[(size_t)b * 512 + t] = s;
    const float* nb = nl + (size_t)b * NG * (NM * NE);
    float s2 = 0.f;
    for (int g = 0; g < NG; ++g) s2 += nb[g * (NM * NE) + t];
    sums[(size_t)b * 512 + 256 + t] = s2;
}

// ---------------------------------------------------------------------------
// Mega kernel: grid 320 x 512 threads, __launch_bounds__(512, 2).
//   blocks 0..63   : IPF + final scale + integerization (b = blockIdx.x)
//   blocks 64..319 : loss partials (4 d-chunks x 64 b)
// LB(512,2): 8-wave block at 2 waves/EU => VGPR cap 256 => y0[4][32] fits
// in registers with NO spill (rounds 5-7 lesson: 1024-thr shape is capped
// at 64 VGPRs by the compiler and spills everything; 512-thr default cap
// of 128 still spilled ~17 MB).
// ---------------------------------------------------------------------------

// ---- IPF path: thread owns d = 4t..4t+3 full-column (all 32 g) ----
__device__ __forceinline__ void ipf_path(
        const float* __restrict__ xp, const int* __restrict__ tsum,
        float* __restrict__ out, float* smem, int b, int t) {
    const int lane = t & 63, w = t >> 6;      // wave 0..7
    const int d0 = t * 4;
    const bool valid = (d0 < ND);             // t < 500
    const int g_own = (lane >> 1) & 31;

    float* wred = smem;                       // [2][8][32] floats, dbuf

    // load y0 = max(x_pred, 0)
    float y0r[4][NG];
    #pragma unroll
    for (int g = 0; g < NG; ++g) {
        float4 v = make_float4(0.f, 0.f, 0.f, 0.f);
        if (valid) v = *(const float4*)(xp + (size_t)(b * NG + g) * ND + d0);
        y0r[0][g] = fmaxf(v.x, 0.f);
        y0r[1][g] = fmaxf(v.y, 0.f);
        y0r[2][g] = fmaxf(v.z, 0.f);
        y0r[3][g] = fmaxf(v.w, 0.f);
    }
    float Cc[4] = {0.f, 0.f, 0.f, 0.f};
    if (valid) {
        const int4 ci = *(const int4*)(tsum + (size_t)b * ND + d0);
        Cc[0] = (float)ci.x; Cc[1] = (float)ci.y; Cc[2] = (float)ci.z; Cc[3] = (float)ci.w;
    }
    float Ac[4] = {1.f, 1.f, 1.f, 1.f};
    float Bown = 1.f;                         // lane-pair's B[g_own]
    float Rown;                               // lane-pair's R[g_own]

    // prologue: row anchors R (buf 0)
    {
        float v[NG];
        #pragma unroll
        for (int g = 0; g < NG; ++g)
            v[g] = y0r[0][g] + y0r[1][g] + y0r[2][g] + y0r[3][g];
        const float tot = wave_sum32(v, lane);
        if ((lane & 1) == 0) wred[w * NG + g_own] = tot;
        __syncthreads();
        float s = 0.f;
        #pragma unroll
        for (int w2 = 0; w2 < 8; ++w2) s += wred[w2 * NG + g_own];
        Rown = s;
    }

    // 60 IPF iterations, ONE barrier each (double-buffered wred)
    for (int q = 1; q <= 60; ++q) {
        float Bg[NG];
        #pragma unroll
        for (int g = 0; g < NG; ++g) Bg[g] = __shfl(Bown, 2 * g);
        // column phase (thread-local)
        float s0 = 0.f, s1 = 0.f, s2 = 0.f, s3 = 0.f;
        #pragma unroll
        for (int g = 0; g < NG; ++g) {
            const float bg = Bg[g];
            s0 += y0r[0][g] * bg; s1 += y0r[1][g] * bg;
            s2 += y0r[2][g] * bg; s3 += y0r[3][g] * bg;
        }
        Ac[0] *= clampf(Cc[0] / fmaxf(Ac[0] * s0, 1e-12f), 0.75f, 1.25f);
        Ac[1] *= clampf(Cc[1] / fmaxf(Ac[1] * s1, 1e-12f), 0.75f, 1.25f);
        Ac[2] *= clampf(Cc[2] / fmaxf(Ac[2] * s2, 1e-12f), 0.75f, 1.25f);
        Ac[3] *= clampf(Cc[3] / fmaxf(Ac[3] * s3, 1e-12f), 0.75f, 1.25f);
        // row phase
        float v[NG];
        #pragma unroll
        for (int g = 0; g < NG; ++g)
            v[g] = y0r[0][g] * Ac[0] + y0r[1][g] * Ac[1]
                 + y0r[2][g] * Ac[2] + y0r[3][g] * Ac[3];
        const float tot = wave_sum32(v, lane);
        const int buf = (q & 1) * (8 * NG);
        if ((lane & 1) == 0) wred[buf + w * NG + g_own] = tot;
        __syncthreads();
        float s = 0.f;
        #pragma unroll
        for (int w2 = 0; w2 < 8; ++w2) s += wred[buf + w2 * NG + g_own];
        Bown *= clampf(Rown / fmaxf(Bown * s, 1e-12f), 0.75f, 1.25f);
    }

    // epilogue: final scale + exact integerization, thread-local per d.
    // NOTE: no dynamic array indexing anywhere (rank-based neg branch =
    // the reference's own formulation) so fr/yv stay in registers.
    if (!valid) return;
    float Bg[NG];
    #pragma unroll
    for (int g = 0; g < NG; ++g) Bg[g] = __shfl(Bown, 2 * g);

    #pragma unroll
    for (int j = 0; j < 4; ++j) {
        float fr[NG];
        int   yv[NG];
        float s = 0.f;
        #pragma unroll
        for (int g = 0; g < NG; ++g) {
            const float z = y0r[j][g] * Ac[j] * Bg[g];
            fr[g] = z;
            s += z;
        }
        const float F = Cc[j] / fmaxf(s, 1e-12f);
        int isum = 0;
        #pragma unroll
        for (int g = 0; g < NG; ++g) {
            const float y = fr[g] * F;
            const float fl = floorf(y);
            yv[g] = (int)fl;
            fr[g] = y - fl;
            isum += yv[g];
        }
        const int Ci = (int)Cc[j];
        const int need = Ci - isum;
        const int pos = max(need, 0);
        const int q = pos >> 5;
        const int r = pos & 31;
        #pragma unroll
        for (int g = 0; g < NG; ++g) yv[g] += q;
        #pragma unroll
        for (int g = 0; g < NG; ++g) {       // stable DESCENDING rank on frac
            int rank = 0;
            #pragma unroll
            for (int h = 0; h < NG; ++h) {
                if (h == g) continue;
                rank += (h < g) ? (fr[h] >= fr[g] ? 1 : 0) : (fr[h] > fr[g] ? 1 : 0);
            }
            if (rank < r) yv[g] += 1;
        }
        // negative residual: one-shot ascending rank among yv>0 (== reference)
        int neg = max(-need, 0);
        neg = min(neg, isum);                 // post-add sum == isum when need<0
        if (__builtin_expect(neg > 0, 0)) {
            const int q2 = neg >> 5;
            int removed = 0;
            #pragma unroll
            for (int g = 0; g < NG; ++g) {
                const int yb = yv[g];
                const int yn = max(yb - q2, 0);
                removed += yb - yn;
                yv[g] = yn;
            }
            const int r2 = neg - removed;
            if (r2 > 0) {
                const float INF = __builtin_inff();
                #pragma unroll
                for (int g = 0; g < NG; ++g) {
                    const float fg = (yv[g] > 0) ? fr[g] : INF;
                    int rank = 0;
                    #pragma unroll
                    for (int h = 0; h < NG; ++h) {
                        if (h == g) continue;
                        const float fh = (yv[h] > 0) ? fr[h] : INF;
                        rank += (h < g) ? (fh <= fg ? 1 : 0) : (fh < fg ? 1 : 0);
                    }
                    if (rank < r2) yv[g] = max(yv[g] - 1, 0);
                }
            }
        }
        #pragma unroll
        for (int g = 0; g < NG; ++g)
            out[1 + (size_t)(b * NG + g) * ND + (d0 + j)] = (float)yv[g];
    }
}

// ---- loss-partials path: 256 blocks = 4 chunks x 64 b, 512 threads ----
// Uses precomputed g-sums (k0): no per-block x/noise staging.
__device__ __forceinline__ void loss_path(
        const float* __restrict__ sums, const float* __restrict__ tgt,
        const float* __restrict__ W, const float* __restrict__ bias,
        float* __restrict__ res2, float* smem, int cx, int b, int t) {
    float* xsl = smem;                 // 256
    float* nsl = smem + 256;           // 256
    float* tgl = smem + 512;           // 504
    float* pt  = smem + 1016;          // 16 x 504

    if (t < 256) {
        xsl[t] = sums[(size_t)b * 512 + t];
        nsl[t] = sums[(size_t)b * 512 + 256 + t];
    }

    int tm = 0, tn = 0;
    if (t >= 16 && t < 152) {
        int p = t - 16;
        for (int m = 0; m < NM; ++m) {
            int c = NM - m;
            if (p < c) { tm = m; tn = m + p; break; }
            p -= c;
        }
    }
    __syncthreads();

    const int d = cx * 500 + t;
    if (t < 500) {
        tgl[t] = tgt[b * ND + d];
        float xw = 0.f;
        #pragma unroll 8
        for (int k = 0; k < NDIN; ++k) xw += xsl[k] * W[(size_t)k * ND + d];
        float we[NE];
        #pragma unroll
        for (int e = 0; e < NE; ++e) we[e] = W[(size_t)(NDIN + e) * ND + d];
        const float base0 = xw + (float)NG * bias[d];
        #pragma unroll
        for (int m = 0; m < NM; ++m) {
            float pm = base0;
            #pragma unroll
            for (int e = 0; e < NE; ++e) pm += nsl[m * NE + e] * we[e];
            pt[m * 504 + t] = pm;
        }
    }
    if (t < 64) {                      // zero-pad cols 500..503 (16 m x 4)
        pt[(t >> 2) * 504 + 500 + (t & 3)] = 0.f;
        if (t < 4) tgl[500 + t] = 0.f;
    }
    __syncthreads();

    float acc = 0.f;
    if (t < 16) {
        const float4* pa  = (const float4*)&pt[t * 504];
        const float4* tga = (const float4*)&tgl[0];
        for (int i = 0; i < 126; ++i) {
            float4 pv = pa[i], tv = tga[i];
            float e0 = pv.x - tv.x, e1 = pv.y - tv.y, e2 = pv.z - tv.z, e3 = pv.w - tv.w;
            acc += e0 * e0 + e1 * e1 + e2 * e2 + e3 * e3;
        }
    } else if (t < 152) {
        const float4* pa = (const float4*)&pt[tm * 504];
        const float4* pb = (const float4*)&pt[tn * 504];
        for (int i = 0; i < 126; ++i) {
            float4 u = pa[i], v = pb[i];
            acc += u.x * v.x + u.y * v.y + u.z * v.z + u.w * v.w;
        }
    }
    if (t < 152) res2[((size_t)b * NCH + cx) * 152 + t] = acc;
}

extern "C" __global__ __launch_bounds__(512, 2)
void mega(const float* __restrict__ sums, const float* __restrict__ tgt,
          const float* __restrict__ W, const float* __restrict__ bias,
          const float* __restrict__ xp, const int* __restrict__ tsum,
          float* __restrict__ out, float* __restrict__ res2) {
    __shared__ float smem[9080];       // 36.3 KB (loss path), IPF uses 512
    const int bid = blockIdx.x;
    const int t = threadIdx.x;
    if (bid < NB) {
        ipf_path(xp, tsum, out, smem, bid, t);
    } else {
        const int q = bid - NB;        // 0..255 -> 4 chunks x 64 b
        loss_path(sums, tgt, W, bias, res2, smem, q & 3, q >> 2, t);
    }
}

// K2b: combine the 4 d-chunk partials per b and accumulate the loss.
extern "C" __global__ __launch_bounds__(64)
void k2b_combine(const float* __restrict__ res2, float* __restrict__ out) {
    const int b = blockIdx.x, t = threadIdx.x;
    __shared__ float res[152];
    for (int tau = t; tau < 152; tau += 64) {
        float s = 0.f;
        #pragma unroll
        for (int c = 0; c < NCH; ++c) s += res2[((size_t)b * NCH + c) * 152 + tau];
        res[tau] = s;
    }
    __syncthreads();
    if (t == 0) {
        float conf = 0.f;
        for (int m = 0; m < NM; ++m) conf += sqrtf(res[m]);
        conf *= (1.f / NM);
        float pd = 0.f;
        for (int m = 0; m < NM; ++m) {
            const int offm = 16 + m * NM - m * (m - 1) / 2;
            const float sqm = res[offm];
            for (int n = m + 1; n < NM; ++n) {
                const int offn = 16 + n * NM - n * (n - 1) / 2;
                const float sqn = res[offn];
                const float inn = res[offm + (n - m)];
                pd += sqrtf(fmaxf(sqm + sqn - 2.f * inn, 1e-6f));
            }
        }
        pd = 2.f * pd / (float)(NM * (NM - 1));
        atomicAdd(out, (conf - 0.5f * pd) * (1.f / NB));
    }
}

// ---------------------------------------------------------------------------
// K3: x_pred = softplus(concat(x, noise_sample) @ W + bias) -> ws.
// Grid (2, 256), 256 threads; thread owns 4 d x 8 rows (float4 W loads).
// ---------------------------------------------------------------------------
extern "C" __global__ __launch_bounds__(256)
void k3_xpred(const float* __restrict__ x, const float* __restrict__ nsamp,
              const float* __restrict__ W, const float* __restrict__ bias,
              float* __restrict__ xp) {
    const int dx = blockIdx.x;     // 0..1
    const int rb = blockIdx.y;     // 0..255
    const int t  = threadIdx.x;
    __shared__ float xr[8][NK];
    #pragma unroll
    for (int r = 0; r < 8; ++r) {
        const int row = rb * 8 + r;
        xr[r][t] = x[(size_t)row * NDIN + t];
        if (t < NE) xr[r][NDIN + t] = nsamp[row * NE + t];
    }
    __syncthreads();
    if (t >= 250) return;
    const int d = dx * 1000 + 4 * t;
    float acc[8][4];
    #pragma unroll
    for (int r = 0; r < 8; ++r) {
        acc[r][0] = 0.f; acc[r][1] = 0.f; acc[r][2] = 0.f; acc[r][3] = 0.f;
    }
    for (int k = 0; k < NK; k += 4) {
        float4 w[4];
        #pragma unroll
        for (int kk = 0; kk < 4; ++kk) w[kk] = *(const float4*)&W[(size_t)(k + kk) * ND + d];
        #pragma unroll
        for (int r = 0; r < 8; ++r) {
            const float4 xv = *(const float4*)&xr[r][k];
            acc[r][0] += xv.x * w[0].x + xv.y * w[1].x + xv.z * w[2].x + xv.w * w[3].x;
            acc[r][1] += xv.x * w[0].y + xv.y * w[1].y + xv.z * w[2].y + xv.w * w[3].y;
            acc[r][2] += xv.x * w[0].z + xv.y * w[1].z + xv.z * w[2].z + xv.w * w[3].z;
            acc[r][3] += xv.x * w[0].w + xv.y * w[1].w + xv.z * w[2].w + xv.w * w[3].w;
        }
    }
    const float4 bv = *(const float4*)&bias[d];
    #pragma unroll
    for (int r = 0; r < 8; ++r) {
        float4 o;
        o.x = softplusf(acc[r][0] + bv.x);
        o.y = softplusf(acc[r][1] + bv.y);
        o.z = softplusf(acc[r][2] + bv.z);
        o.w = softplusf(acc[r][3] + bv.w);
        *(float4*)&xp[(size_t)(rb * 8 + r) * ND + d] = o;
    }
}

// ---------------------------------------------------------------------------
extern "C" void kernel_launch(void* const* d_in, const int* in_sizes, int n_in,
                              void* d_out, int out_size, void* d_ws, size_t ws_size,
                              hipStream_t stream) {
    const float* x     = (const float*)d_in[0];
    const float* tgt   = (const float*)d_in[1];
    const int*   tsum  = (const int*)d_in[2];
    const float* W     = (const float*)d_in[3];
    const float* bias  = (const float*)d_in[4];
    const float* nl    = (const float*)d_in[5];
    const float* nsamp = (const float*)d_in[6];
    float* out = (float*)d_out;
    float* xp  = (float*)d_ws;                         // 2048*2000 floats

    (void)in_sizes; (void)n_in; (void)out_size; (void)ws_size;

    const size_t XPB  = (size_t)2048 * 2000 * 4;       // 16,384,000 B
    const size_t RESB = (size_t)NB * NCH * 152 * 4;    // 155,648 B
    float* res2 = (float*)((char*)d_ws + XPB);
    float* sums = (float*)((char*)d_ws + XPB + RESB);  // 64 x 512 floats

    hipMemsetAsync(d_out, 0, sizeof(float), stream);   // loss accumulator

    hipLaunchKernelGGL(k0_sums, dim3(NB), dim3(256), 0, stream, x, nl, sums);
    hipLaunchKernelGGL(k3_xpred, dim3(2, 256), dim3(256), 0, stream,
                       x, nsamp, W, bias, xp);
    hipLaunchKernelGGL(mega, dim3(NB + NB * NCH), dim3(512), 0, stream,
                       sums, tgt, W, bias, xp, tsum, out, res2);
    hipLaunchKernelGGL(k2b_combine, dim3(NB), dim3(64), 0, stream, res2, out);
}

// Round 9
// 316.747 us; speedup vs baseline: 1.7547x; 1.7547x over previous
//
#include <hip/hip_runtime.h>
#include <math.h>

// Problem constants (match reference)
#define NB   64     // num_groups (B)
#define NG   32     // group_size (G)
#define ND   2000   // output dim D
#define NM   16     // m_samples
#define NE   16     // noise dim
#define NDIN 256
#define NK   272    // DIN + E

__device__ __forceinline__ float clampf(float v, float lo, float hi) {
    return fminf(fmaxf(v, lo), hi);
}

__device__ __forceinline__ float softplusf(float v) {
    return (v > 20.f) ? v : log1pf(expf(v));
}

// Broadcast lane `lane`'s value to all lanes as a WAVE-UNIFORM (SGPR) value.
// Key register-pressure trick: B[32] lives in SGPRs, not VGPRs.
__device__ __forceinline__ float readlane_f(float v, int lane) {
    return __int_as_float(__builtin_amdgcn_readlane(__float_as_int(v), lane));
}

// Fully-packed butterfly: reduce v[0..31] (per-g partials) across 64 lanes in
// 32 shuffles.  Returns the wave total for g = (lane>>1)&31 (dup on pairs).
// HW-verified rounds 3-8.
__device__ __forceinline__ float wave_sum32(float v[NG], int lane) {
    {   const bool hi = (lane & 32) != 0;
        #pragma unroll
        for (int k = 0; k < 16; ++k) {
            float s = hi ? v[k] : v[k + 16];
            float r = __shfl_xor(s, 32);
            v[k] = (hi ? v[k + 16] : v[k]) + r;
        }
    }
    {   const bool hi = (lane & 16) != 0;
        #pragma unroll
        for (int k = 0; k < 8; ++k) {
            float s = hi ? v[k] : v[k + 8];
            float r = __shfl_xor(s, 16);
            v[k] = (hi ? v[k + 8] : v[k]) + r;
        }
    }
    {   const bool hi = (lane & 8) != 0;
        #pragma unroll
        for (int k = 0; k < 4; ++k) {
            float s = hi ? v[k] : v[k + 4];
            float r = __shfl_xor(s, 8);
            v[k] = (hi ? v[k + 4] : v[k]) + r;
        }
    }
    {   const bool hi = (lane & 4) != 0;
        #pragma unroll
        for (int k = 0; k < 2; ++k) {
            float s = hi ? v[k] : v[k + 2];
            float r = __shfl_xor(s, 4);
            v[k] = (hi ? v[k + 2] : v[k]) + r;
        }
    }
    {   const bool hi = (lane & 2) != 0;
        float s = hi ? v[0] : v[1];
        float r = __shfl_xor(s, 2);
        v[0] = (hi ? v[1] : v[0]) + r;
    }
    v[0] += __shfl_xor(v[0], 1);
    return v[0];
}

// ---------------------------------------------------------------------------
// Mega kernel: grid 576 x 512 threads, __launch_bounds__(512, 1).
//   blocks 0..63   : IPF + final scale + integerization (b = blockIdx.x)
//   blocks 64..575 : loss partials (8 d-chunks x 64 b)
// LB(512, 1): min 1 wave/EU => VGPR cap 512 => the IPF live set (~200:
// y0[4][32]=128 + butterfly v[32] + temps; B[32] in SGPRs via readlane)
// fits with ZERO spill.  (Rounds 5-8 lesson: default / (512,2) / 1024-thr
// all capped VGPRs at 128/64 and spilled y0 to scratch: +16..30 MB
// WRITE_SIZE and 2x time.  1 block/CU is what IPF had anyway.)
// ---------------------------------------------------------------------------

// ---- IPF path: thread owns d = 4t..4t+3 full-column (all 32 g) ----
__device__ __forceinline__ void ipf_path(
        const float* __restrict__ xp, const int* __restrict__ tsum,
        float* __restrict__ out, float* smem, int b, int t) {
    const int lane = t & 63, w = t >> 6;      // wave 0..7
    const int d0 = t * 4;
    const bool valid = (d0 < ND);             // t < 500
    const int g_own = (lane >> 1) & 31;

    float* wred = smem;                       // [2][8][32] floats, dbuf

    // load y0 = max(x_pred, 0)
    float y0r[4][NG];
    #pragma unroll
    for (int g = 0; g < NG; ++g) {
        float4 v = make_float4(0.f, 0.f, 0.f, 0.f);
        if (valid) v = *(const float4*)(xp + (size_t)(b * NG + g) * ND + d0);
        y0r[0][g] = fmaxf(v.x, 0.f);
        y0r[1][g] = fmaxf(v.y, 0.f);
        y0r[2][g] = fmaxf(v.z, 0.f);
        y0r[3][g] = fmaxf(v.w, 0.f);
    }
    float Cc[4] = {0.f, 0.f, 0.f, 0.f};
    if (valid) {
        const int4 ci = *(const int4*)(tsum + (size_t)b * ND + d0);
        Cc[0] = (float)ci.x; Cc[1] = (float)ci.y; Cc[2] = (float)ci.z; Cc[3] = (float)ci.w;
    }
    float Ac[4] = {1.f, 1.f, 1.f, 1.f};
    float Bown = 1.f;                         // lane-pair's B[g_own]
    float Rown;                               // lane-pair's R[g_own]

    // prologue: row anchors R (buf 0)
    {
        float v[NG];
        #pragma unroll
        for (int g = 0; g < NG; ++g)
            v[g] = y0r[0][g] + y0r[1][g] + y0r[2][g] + y0r[3][g];
        const float tot = wave_sum32(v, lane);
        if ((lane & 1) == 0) wred[w * NG + g_own] = tot;
        __syncthreads();
        float s = 0.f;
        #pragma unroll
        for (int w2 = 0; w2 < 8; ++w2) s += wred[w2 * NG + g_own];
        Rown = s;
    }

    // 60 IPF iterations, ONE barrier each (double-buffered wred)
    for (int q = 1; q <= 60; ++q) {
        // column phase (thread-local; B broadcast via readlane -> SGPRs)
        float s0 = 0.f, s1 = 0.f, s2 = 0.f, s3 = 0.f;
        #pragma unroll
        for (int g = 0; g < NG; ++g) {
            const float bg = readlane_f(Bown, 2 * g);
            s0 += y0r[0][g] * bg; s1 += y0r[1][g] * bg;
            s2 += y0r[2][g] * bg; s3 += y0r[3][g] * bg;
        }
        Ac[0] *= clampf(Cc[0] / fmaxf(Ac[0] * s0, 1e-12f), 0.75f, 1.25f);
        Ac[1] *= clampf(Cc[1] / fmaxf(Ac[1] * s1, 1e-12f), 0.75f, 1.25f);
        Ac[2] *= clampf(Cc[2] / fmaxf(Ac[2] * s2, 1e-12f), 0.75f, 1.25f);
        Ac[3] *= clampf(Cc[3] / fmaxf(Ac[3] * s3, 1e-12f), 0.75f, 1.25f);
        // row phase
        float v[NG];
        #pragma unroll
        for (int g = 0; g < NG; ++g)
            v[g] = y0r[0][g] * Ac[0] + y0r[1][g] * Ac[1]
                 + y0r[2][g] * Ac[2] + y0r[3][g] * Ac[3];
        const float tot = wave_sum32(v, lane);
        const int buf = (q & 1) * (8 * NG);
        if ((lane & 1) == 0) wred[buf + w * NG + g_own] = tot;
        __syncthreads();
        float s = 0.f;
        #pragma unroll
        for (int w2 = 0; w2 < 8; ++w2) s += wred[buf + w2 * NG + g_own];
        Bown *= clampf(Rown / fmaxf(Bown * s, 1e-12f), 0.75f, 1.25f);
    }

    // epilogue: final scale + exact integerization, thread-local per d.
    // Rank-based neg branch (reference-equivalent): NO dynamic array
    // indexing anywhere, so fr/yv stay in registers.
    if (!valid) return;

    unsigned pk[NG];
    #pragma unroll
    for (int g = 0; g < NG; ++g) pk[g] = 0u;

    #pragma unroll
    for (int j = 0; j < 4; ++j) {
        float fr[NG];
        int   yv[NG];
        float s = 0.f;
        #pragma unroll
        for (int g = 0; g < NG; ++g) {
            const float z = y0r[j][g] * Ac[j] * readlane_f(Bown, 2 * g);
            fr[g] = z;
            s += z;
        }
        const float F = Cc[j] / fmaxf(s, 1e-12f);
        int isum = 0;
        #pragma unroll
        for (int g = 0; g < NG; ++g) {
            const float y = fr[g] * F;
            const float fl = floorf(y);
            yv[g] = (int)fl;
            fr[g] = y - fl;
            isum += yv[g];
        }
        const int Ci = (int)Cc[j];
        const int need = Ci - isum;
        const int pos = max(need, 0);
        const int q = pos >> 5;
        const int r = pos & 31;
        #pragma unroll
        for (int g = 0; g < NG; ++g) yv[g] += q;
        #pragma unroll
        for (int g = 0; g < NG; ++g) {       // stable DESCENDING rank on frac
            int rank = 0;
            #pragma unroll
            for (int h = 0; h < NG; ++h) {
                if (h == g) continue;
                rank += (h < g) ? (fr[h] >= fr[g] ? 1 : 0) : (fr[h] > fr[g] ? 1 : 0);
            }
            if (rank < r) yv[g] += 1;
        }
        // negative residual: one-shot ascending rank among yv>0 (== reference)
        int neg = max(-need, 0);
        neg = min(neg, isum);
        if (__builtin_expect(neg > 0, 0)) {
            const int q2 = neg >> 5;
            int removed = 0;
            #pragma unroll
            for (int g = 0; g < NG; ++g) {
                const int yb = yv[g];
                const int yn = max(yb - q2, 0);
                removed += yb - yn;
                yv[g] = yn;
            }
            const int r2 = neg - removed;
            if (r2 > 0) {
                const float INF = __builtin_inff();
                #pragma unroll
                for (int g = 0; g < NG; ++g) {
                    const float fg = (yv[g] > 0) ? fr[g] : INF;
                    int rank = 0;
                    #pragma unroll
                    for (int h = 0; h < NG; ++h) {
                        if (h == g) continue;
                        const float fh = (yv[h] > 0) ? fr[h] : INF;
                        rank += (h < g) ? (fh <= fg ? 1 : 0) : (fh < fg ? 1 : 0);
                    }
                    if (rank < r2) yv[g] = max(yv[g] - 1, 0);
                }
            }
        }
        #pragma unroll
        for (int g = 0; g < NG; ++g)
            pk[g] |= ((unsigned)yv[g]) << (8 * j);   // yv <= C <= 199 < 256
    }
    // 4 consecutive dword stores per g: lanes cover disjoint 16B spans =>
    // full cacheline utilization (round-5 verified, WRITE ~= output size)
    #pragma unroll
    for (int g = 0; g < NG; ++g) {
        float* op = &out[1 + (size_t)(b * NG + g) * ND + d0];
        op[0] = (float)(pk[g] & 0xffu);
        op[1] = (float)((pk[g] >> 8) & 0xffu);
        op[2] = (float)((pk[g] >> 16) & 0xffu);
        op[3] = (float)((pk[g] >> 24) & 0xffu);
    }
}

// ---- loss-partials path: 512 blocks = 8 d-chunks x 64 b (round-5 exact) ---
__device__ __forceinline__ void loss_path(
        const float* __restrict__ x, const float* __restrict__ nl,
        const float* __restrict__ tgt, const float* __restrict__ W,
        const float* __restrict__ bias, float* __restrict__ res2,
        float* smem, int cx, int b, int t) {
    float* xsl = smem;                 // 256
    float* nsl = smem + 256;           // 256
    float* tgl = smem + 512;           // 252
    float* pt  = smem + 764;           // 16 x 252

    if (t < 256) {
        const float* xb = x + (size_t)b * NG * NDIN;
        float s = 0.f;
        for (int g = 0; g < NG; ++g) s += xb[g * NDIN + t];
        xsl[t] = s;
        const float* nb = nl + (size_t)b * NG * (NM * NE);
        float s2 = 0.f;
        for (int g = 0; g < NG; ++g) s2 += nb[g * (NM * NE) + t];
        nsl[t] = s2;
    }

    int tm = 0, tn = 0;
    if (t >= 16 && t < 152) {
        int p = t - 16;
        for (int m = 0; m < NM; ++m) {
            int c = NM - m;
            if (p < c) { tm = m; tn = m + p; break; }
            p -= c;
        }
    }
    __syncthreads();

    const int d = cx * 250 + t;
    if (t < 250) {
        tgl[t] = tgt[b * ND + d];
        float xw = 0.f;
        #pragma unroll 8
        for (int k = 0; k < NDIN; ++k) xw += xsl[k] * W[(size_t)k * ND + d];
        float we[NE];
        #pragma unroll
        for (int e = 0; e < NE; ++e) we[e] = W[(size_t)(NDIN + e) * ND + d];
        const float base0 = xw + (float)NG * bias[d];
        #pragma unroll
        for (int m = 0; m < NM; ++m) {
            float pm = base0;
            #pragma unroll
            for (int e = 0; e < NE; ++e) pm += nsl[m * NE + e] * we[e];
            pt[m * 252 + t] = pm;
        }
    }
    if (t < 32) {                      // zero-pad cols 250,251
        pt[(t >> 1) * 252 + 250 + (t & 1)] = 0.f;
        if (t < 2) tgl[250 + t] = 0.f;
    }
    __syncthreads();

    float acc = 0.f;
    if (t < 16) {
        const float4* pa  = (const float4*)&pt[t * 252];
        const float4* tga = (const float4*)&tgl[0];
        for (int i = 0; i < 63; ++i) {
            float4 pv = pa[i], tv = tga[i];
            float e0 = pv.x - tv.x, e1 = pv.y - tv.y, e2 = pv.z - tv.z, e3 = pv.w - tv.w;
            acc += e0 * e0 + e1 * e1 + e2 * e2 + e3 * e3;
        }
    } else if (t < 152) {
        const float4* pa = (const float4*)&pt[tm * 252];
        const float4* pb = (const float4*)&pt[tn * 252];
        for (int i = 0; i < 63; ++i) {
            float4 u = pa[i], v = pb[i];
            acc += u.x * v.x + u.y * v.y + u.z * v.z + u.w * v.w;
        }
    }
    if (t < 152) res2[((size_t)b * 8 + cx) * 152 + t] = acc;
}

extern "C" __global__ __launch_bounds__(512, 1)
void mega(const float* __restrict__ x, const float* __restrict__ nl,
          const float* __restrict__ tgt, const float* __restrict__ W,
          const float* __restrict__ bias, const float* __restrict__ xp,
          const int* __restrict__ tsum, float* __restrict__ out,
          float* __restrict__ res2) {
    __shared__ float smem[4800];       // 19.2 KB, union of both paths
    const int bid = blockIdx.x;
    const int t = threadIdx.x;
    if (bid < NB) {
        ipf_path(xp, tsum, out, smem, bid, t);
    } else {
        const int q = bid - NB;        // 0..511 -> 8 chunks x 64 b
        loss_path(x, nl, tgt, W, bias, res2, smem, q & 7, q >> 3, t);
    }
}

// K2b: combine the 8 d-chunk partials per b and accumulate the loss.
extern "C" __global__ __launch_bounds__(64)
void k2b_combine(const float* __restrict__ res2, float* __restrict__ out) {
    const int b = blockIdx.x, t = threadIdx.x;
    __shared__ float res[152];
    for (int tau = t; tau < 152; tau += 64) {
        float s = 0.f;
        #pragma unroll
        for (int c = 0; c < 8; ++c) s += res2[((size_t)b * 8 + c) * 152 + tau];
        res[tau] = s;
    }
    __syncthreads();
    if (t == 0) {
        float conf = 0.f;
        for (int m = 0; m < NM; ++m) conf += sqrtf(res[m]);
        conf *= (1.f / NM);
        float pd = 0.f;
        for (int m = 0; m < NM; ++m) {
            const int offm = 16 + m * NM - m * (m - 1) / 2;
            const float sqm = res[offm];
            for (int n = m + 1; n < NM; ++n) {
                const int offn = 16 + n * NM - n * (n - 1) / 2;
                const float sqn = res[offn];
                const float inn = res[offm + (n - m)];
                pd += sqrtf(fmaxf(sqm + sqn - 2.f * inn, 1e-6f));
            }
        }
        pd = 2.f * pd / (float)(NM * (NM - 1));
        atomicAdd(out, (conf - 0.5f * pd) * (1.f / NB));
    }
}

// ---------------------------------------------------------------------------
// K3: x_pred = softplus(concat(x, noise_sample) @ W + bias) -> ws.
// Grid (2, 256), 256 threads; thread owns 4 d x 8 rows (float4 W loads).
// ---------------------------------------------------------------------------
extern "C" __global__ __launch_bounds__(256)
void k3_xpred(const float* __restrict__ x, const float* __restrict__ nsamp,
              const float* __restrict__ W, const float* __restrict__ bias,
              float* __restrict__ xp) {
    const int dx = blockIdx.x;     // 0..1
    const int rb = blockIdx.y;     // 0..255
    const int t  = threadIdx.x;
    __shared__ float xr[8][NK];
    #pragma unroll
    for (int r = 0; r < 8; ++r) {
        const int row = rb * 8 + r;
        xr[r][t] = x[(size_t)row * NDIN + t];
        if (t < NE) xr[r][NDIN + t] = nsamp[row * NE + t];
    }
    __syncthreads();
    if (t >= 250) return;
    const int d = dx * 1000 + 4 * t;
    float acc[8][4];
    #pragma unroll
    for (int r = 0; r < 8; ++r) {
        acc[r][0] = 0.f; acc[r][1] = 0.f; acc[r][2] = 0.f; acc[r][3] = 0.f;
    }
    for (int k = 0; k < NK; k += 4) {
        float4 w[4];
        #pragma unroll
        for (int kk = 0; kk < 4; ++kk) w[kk] = *(const float4*)&W[(size_t)(k + kk) * ND + d];
        #pragma unroll
        for (int r = 0; r < 8; ++r) {
            const float4 xv = *(const float4*)&xr[r][k];
            acc[r][0] += xv.x * w[0].x + xv.y * w[1].x + xv.z * w[2].x + xv.w * w[3].x;
            acc[r][1] += xv.x * w[0].y + xv.y * w[1].y + xv.z * w[2].y + xv.w * w[3].y;
            acc[r][2] += xv.x * w[0].z + xv.y * w[1].z + xv.z * w[2].z + xv.w * w[3].z;
            acc[r][3] += xv.x * w[0].w + xv.y * w[1].w + xv.z * w[2].w + xv.w * w[3].w;
        }
    }
    const float4 bv = *(const float4*)&bias[d];
    #pragma unroll
    for (int r = 0; r < 8; ++r) {
        float4 o;
        o.x = softplusf(acc[r][0] + bv.x);
        o.y = softplusf(acc[r][1] + bv.y);
        o.z = softplusf(acc[r][2] + bv.z);
        o.w = softplusf(acc[r][3] + bv.w);
        *(float4*)&xp[(size_t)(rb * 8 + r) * ND + d] = o;
    }
}

// ---------------------------------------------------------------------------
extern "C" void kernel_launch(void* const* d_in, const int* in_sizes, int n_in,
                              void* d_out, int out_size, void* d_ws, size_t ws_size,
                              hipStream_t stream) {
    const float* x     = (const float*)d_in[0];
    const float* tgt   = (const float*)d_in[1];
    const int*   tsum  = (const int*)d_in[2];
    const float* W     = (const float*)d_in[3];
    const float* bias  = (const float*)d_in[4];
    const float* nl    = (const float*)d_in[5];
    const float* nsamp = (const float*)d_in[6];
    float* out = (float*)d_out;
    float* xp  = (float*)d_ws;                         // 2048*2000 floats

    (void)in_sizes; (void)n_in; (void)out_size; (void)ws_size;

    const size_t XPB = (size_t)2048 * 2000 * 4;        // 16,384,000 B
    float* res2 = (float*)((char*)d_ws + XPB);         // 64*8*152 floats

    hipMemsetAsync(d_out, 0, sizeof(float), stream);   // loss accumulator

    hipLaunchKernelGGL(k3_xpred, dim3(2, 256), dim3(256), 0, stream,
                       x, nsamp, W, bias, xp);
    hipLaunchKernelGGL(mega, dim3(NB + 512), dim3(512), 0, stream,
                       x, nl, tgt, W, bias, xp, tsum, out, res2);
    hipLaunchKernelGGL(k2b_combine, dim3(NB), dim3(64), 0, stream, res2, out);
}